// Round 9
// baseline (86.777 us; speedup 1.0000x reference)
//
#include <hip/hip_runtime.h>

#define SEQ   512
#define BATCH 256

// Lane broadcast via v_readlane (imm or SGPR index).
__device__ __forceinline__ float bcast_f(float v, int l) {
    return __int_as_float(__builtin_amdgcn_readlane(__float_as_int(v), l));
}
// gfx950: v_log_f32 is log2, v_exp_f32 is exp2.
__device__ __forceinline__ float flog2(float x) { return __builtin_amdgcn_logf(x); }
__device__ __forceinline__ float fexp2(float x) { return __builtin_amdgcn_exp2f(x); }
// Barrier draining only LDS ops (lgkmcnt), not vmcnt.
__device__ __forceinline__ void lds_barrier() {
    __asm__ __volatile__("s_waitcnt lgkmcnt(0)\ns_barrier" ::: "memory");
}

// One block (512 threads = 8 waves) per batch column.
//
// Wave 0: serial diagonal with a READLANE-FREE chain. The carry em is
// replicated in all lanes and advanced scalarly:
//     tmp = -(a + c*em)                (vector fma, all lanes)
//     t   = exp2(tmp * Ld[j])          (Ld = subdiag log, readlane'd off-chain)
//     em' = sB + t                     (sB = readlane(acc, j+1), 1 step of slack)
// In the same step the vector sweep acc += exp2(tmp * log(max(xd - xd_j,1)))
// updates all rows of the block (maskless: lanes i<=j add exactly 1.0,
// corrected at publish). The scalar term t is bitwise equal to the vector
// term at lane j+1, so em stays exactly consistent with acc.
//
// Helpers (waves {1,2,3,5,6,7}; wid4 idles to keep SIMD0's trans pipe clean):
// panel (col block J-1 -> row block J) before B1; "deep" block pairs follow a
// static schedule (<=4 pairs/phase, each in its legal window) to balance
// per-phase trans load. Partials merge via LDS atomicAdd.
__global__ void __launch_bounds__(512, 1)
act_r_kernel(const float* __restrict__ sp, const float* __restrict__ w,
             float* __restrict__ out) {
    __shared__ float x_lds[SEQ];
    __shared__ float Ld_lds[SEQ];      // subdiag logs: log2(max(x[i+1]-x[i],1))
    __shared__ float expm_lds[SEQ];
    __shared__ float part_lds[8][64];  // [row block][lane]

    const int b    = blockIdx.x;
    const int tid  = threadIdx.x;
    const int wid  = tid >> 6;
    const int lane = tid & 63;

    const float a   = w[0];
    const float c   = w[1];
    const float s   = w[2];
    const float tau = w[3];
    const float h   = w[4];
    const float scale = 86400.0f * h;

    // Deep-pair schedule: phase J handles pairs (DKt[J][t], DRt[J][t]).
    // Every (K,R) with R-K>=2 appears once, within its window [K+1, R-1].
    const int DN[8]     = {0, 3, 3, 4, 4, 4, 3, 0};
    const int DKt[8][4] = {{0,0,0,0},{0,0,0,0},{1,1,0,0},{2,1,0,2},
                           {3,1,0,2},{4,3,1,2},{5,4,3,0},{0,0,0,0}};
    const int DRt[8][4] = {{0,0,0,0},{2,3,4,0},{3,4,5,0},{4,5,6,5},
                           {5,6,7,6},{6,6,7,7},{7,7,7,0},{0,0,0,0}};

    // Helper column split over waves {1,2,3,5,6,7}: 11,11,11,11,10,10.
    int start = 0, cnt = 0;
    if (wid != 0 && wid != 4) {
        const int slot = (wid < 4) ? (wid - 1) : (wid - 2);   // 0..5
        start = (slot <= 4) ? slot * 11 : 54;
        cnt   = (slot < 4) ? 11 : 10;
    }

    x_lds[tid] = sp[tid * BATCH + b] * scale;
    part_lds[wid][lane] = 0.0f;
    lds_barrier();
    Ld_lds[tid] = (tid < 511) ? flog2(fmaxf(x_lds[tid + 1] - x_lds[tid], 1.0f))
                              : 0.0f;
    lds_barrier();

    const float vna = -a, vnc = -c;

    for (int J = 0; J < 8; ++J) {
        if (J > 0 && cnt > 0) {
            // ---- panel: col block J-1 -> row block J
            const float evec = expm_lds[((J - 1) << 6) | lane];
            const float xjv  = x_lds[((J - 1) << 6) | lane];
            const float xr   = x_lds[(J << 6) | lane];
            float pacc = 0.0f;
#pragma unroll
            for (int k = 0; k < 11; ++k) {
                const int jc = (k < cnt) ? (start + k) : start;
                const float em = bcast_f(evec, jc);
                const float xj = bcast_f(xjv, jc);
                const float L  = flog2(fmaxf(xr - xj, 1.0f));
                const float t  = fexp2(-fmaf(c, em, a) * L);
                pacc += (k < cnt) ? t : 0.0f;
            }
            atomicAdd(&part_lds[J][lane], pacc);
        }
        lds_barrier();  // B1: part_lds[J] complete

        if (wid == 0) {
            float accv = part_lds[J][lane];          // merged off-diag base
            const float xd  = x_lds[(J << 6) | lane];
            const float LdV = Ld_lds[(J << 6) | lane];
            float em = bcast_f(accv, 0);             // expm[64J] (clean lane 0)
            float sB = bcast_f(accv, 1);             // base for row 64J+1
#pragma unroll
            for (int jl = 0; jl < 63; ++jl) {
                const float tmp = fmaf(vnc, em, vna);              // -(a+c*em)
                const float dx  = fmaxf(xd - bcast_f(xd, jl), 1.0f);
                const float tv  = fexp2(tmp * flog2(dx));          // vector terms
                const float t   = fexp2(tmp * bcast_f(LdV, jl));   // chain term
                em = sB + t;                                       // = acc[jl+1]
                accv += tv;
                if (jl < 62) sB = bcast_f(accv, jl + 2);           // off-chain
            }
            expm_lds[(J << 6) | lane] = accv - (float)(63 - lane); // publish
        } else if (cnt > 0) {
            // ---- scheduled deep pairs (overlap the diagonal)
            for (int t2 = 0; t2 < DN[J]; ++t2) {
                const int K = DKt[J][t2], R = DRt[J][t2];
                const float evec = expm_lds[(K << 6) | lane];
                const float xjv  = x_lds[(K << 6) | lane];
                const float xr   = x_lds[(R << 6) | lane];
                float pacc = 0.0f;
#pragma unroll
                for (int k = 0; k < 11; ++k) {
                    const int jc = (k < cnt) ? (start + k) : start;
                    const float em = bcast_f(evec, jc);
                    const float xj = bcast_f(xjv, jc);
                    const float L  = flog2(fmaxf(xr - xj, 1.0f));
                    const float t  = fexp2(-fmaf(c, em, a) * L);
                    pacc += (k < cnt) ? t : 0.0f;
                }
                atomicAdd(&part_lds[R][lane], pacc);
            }
        }
        lds_barrier();  // B2: expm block J published
    }

    // ---- epilogue: all 512 threads, one output each (i = tid, skip 0)
    if (tid >= 1) {
        const float inv_ln2 = 1.4426950408889634f;
        const float q = tau / s * inv_ln2 - flog2(expm_lds[tid]) / s;
        out[(tid - 1) * BATCH + b] = 1.0f / (1.0f + fexp2(q));
    }
}

extern "C" void kernel_launch(void* const* d_in, const int* in_sizes, int n_in,
                              void* d_out, int out_size, void* d_ws, size_t ws_size,
                              hipStream_t stream) {
    const float* sp = (const float*)d_in[0];  // [512, 256, 1] f32
    const float* w  = (const float*)d_in[1];  // [5] f32
    float* out = (float*)d_out;               // [511, 256, 1] f32
    (void)in_sizes; (void)n_in; (void)out_size; (void)d_ws; (void)ws_size;

    act_r_kernel<<<dim3(BATCH), dim3(512), 0, stream>>>(sp, w, out);
}